// Round 1
// 502.917 us; speedup vs baseline: 1.1774x; 1.1774x over previous
//
#include <hip/hip_runtime.h>
#include <stdint.h>

// Problem constants
#define NB   512      // batch
#define NL   128      // cycles per sample (GEMM M)
#define NK   900      // 3*F (GEMM K)
#define NKP  928      // K padded to 29*32
#define NKT  29       // K tiles of 32
#define ND   512      // D_MODEL (GEMM N)
#define NDLLM 4096
#define NE   8
#define ASTR 40       // LDS row stride in ushorts (80 B) — bank-conflict-free for b128 reads

typedef __bf16 bf16x8 __attribute__((ext_vector_type(8)));
typedef float  f32x4  __attribute__((ext_vector_type(4)));

// f32 -> bf16 bits, round-to-nearest-even (inputs are finite)
__device__ __forceinline__ unsigned short f2bf(float f) {
  union { float f; uint32_t u; } v; v.f = f;
  uint32_t u = v.u;
  return (unsigned short)((u + 0x7fffu + ((u >> 16) & 1u)) >> 16);
}

// ---------------------------------------------------------------------------
// Kernel 1: gate logits + argmax.  logits[b,e] = DKP[b,:] @ W_gate[:,e] + b_gate[e]
// Top-p with P=0.25,E=8 provably selects exactly argmax with weight exactly 1.0.
// ---------------------------------------------------------------------------
__global__ __launch_bounds__(256) void gate_kernel(
    const float* __restrict__ dkp,    // [NB, 4096]
    const float* __restrict__ Wg,     // [4096, 8]
    const float* __restrict__ bg,     // [8]
    int* __restrict__ eidx)           // [NB]
{
  const int b = blockIdx.x;
  const int t = threadIdx.x;
  float acc[8];
#pragma unroll
  for (int e = 0; e < 8; ++e) acc[e] = 0.f;
  const float* drow = dkp + (size_t)b * NDLLM;
  for (int k = t; k < NDLLM; k += 256) {
    float d = drow[k];
    const float4* w4 = (const float4*)(Wg + (size_t)k * 8);
    float4 w0 = w4[0], w1 = w4[1];
    acc[0] += d * w0.x; acc[1] += d * w0.y; acc[2] += d * w0.z; acc[3] += d * w0.w;
    acc[4] += d * w1.x; acc[5] += d * w1.y; acc[6] += d * w1.z; acc[7] += d * w1.w;
  }
#pragma unroll
  for (int e = 0; e < 8; ++e)
    for (int off = 32; off >= 1; off >>= 1)
      acc[e] += __shfl_down(acc[e], off, 64);

  __shared__ float red[4][8];
  const int wave = t >> 6, lane = t & 63;
  if (lane == 0) {
#pragma unroll
    for (int e = 0; e < 8; ++e) red[wave][e] = acc[e];
  }
  __syncthreads();
  if (t == 0) {
    float best = -1e30f; int bi = 0;
#pragma unroll
    for (int e = 0; e < 8; ++e) {
      float v = red[0][e] + red[1][e] + red[2][e] + red[3][e] + bg[e];
      if (v > best) { best = v; bi = e; }  // strict > matches stable argsort tie-break
    }
    eidx[b] = bi;
  }
}

// ---------------------------------------------------------------------------
// Kernel 2: pack W_tot[e] = W_exp[e] + W_gen[0] + W_gen[1], transposed to
// B^T layout [e][n(512)][k(928)] as bf16 bits, K zero-padded 900->928.
// ---------------------------------------------------------------------------
__global__ __launch_bounds__(256) void pack_kernel(
    const float* __restrict__ Wexp,   // [8, 900, 512]
    const float* __restrict__ Wgen,   // [2, 900, 512]
    unsigned short* __restrict__ Wt)  // [8, 512, 928] bf16 bits
{
  const int nt = blockIdx.x;          // 8 tiles of 64 n
  const int kt = blockIdx.y;          // 29 tiles of 32 k
  const int e  = blockIdx.z;
  const int k0 = kt * 32, n0 = nt * 64;
  __shared__ float tile[32][65];
  const int t = threadIdx.x;
#pragma unroll
  for (int i = 0; i < 8; ++i) {
    int idx = t + i * 256;
    int k = idx >> 6, n = idx & 63;
    int kg = k0 + k;
    float v = 0.f;
    if (kg < NK) {
      size_t off = (size_t)kg * ND + n0 + n;
      v = Wexp[(size_t)e * NK * ND + off] + Wgen[off] + Wgen[(size_t)NK * ND + off];
    }
    tile[k][n] = v;
  }
  __syncthreads();
#pragma unroll
  for (int i = 0; i < 8; ++i) {
    int idx = t + i * 256;
    int n = idx >> 5, k = idx & 31;
    Wt[((size_t)e * ND + n0 + n) * NKP + k0 + k] = f2bf(tile[k][n]);
  }
}

// ---------------------------------------------------------------------------
// Kernel 3: btot[e][d] = b_exp[e][d] + b_gen[0][d] + b_gen[1][d]
// ---------------------------------------------------------------------------
__global__ __launch_bounds__(256) void bias_kernel(
    const float* __restrict__ bexp, const float* __restrict__ bgen,
    float* __restrict__ btot)
{
  int i = blockIdx.x * 256 + threadIdx.x;   // 8*512 = 4096
  int d = i & (ND - 1);
  btot[i] = bexp[i] + bgen[d] + bgen[ND + d];
}

// ---------------------------------------------------------------------------
// Kernel 4: per-batch expert GEMM, fused over all of N.
// One block per b: C[b](128x512) = X[b](128x900) @ Wt[e*[b]].
// 512 threads = 8 waves (2M x 4N), per-wave tile 64x128, K-step 32.
// Double-buffered LDS (A 2x10KB, B 2x40KB, stride-40 pad = bank-conflict-free),
// 2-phase pipeline: issue tile t+1 global loads -> regs, compute tile t,
// barrier, convert+ds_write, barrier (T3-minimum + T14 issue-early/write-late).
// X is read from HBM exactly once (old grid read it 4x across XCDs).
// ---------------------------------------------------------------------------
__global__ __launch_bounds__(512, 2) void gemm_kernel(
    const float* __restrict__ x,              // [NB, NL, NK]
    const unsigned short* __restrict__ Wt,    // [8, 512, 928] bf16 bits
    const float* __restrict__ btot,           // [8, 512]
    const int* __restrict__ eidx,             // [NB]
    float* __restrict__ out)                  // [NB, NL, ND] f32
{
  __shared__ unsigned short As[2][NL * ASTR];   // 2 x 10 KB
  __shared__ unsigned short Bs[2][ND * ASTR];   // 2 x 40 KB   (total 100 KB)

  const int b    = blockIdx.x;
  const int t    = threadIdx.x;
  const int lane = t & 63;
  const int w    = t >> 6;
  const int wm   = (w >> 2) * 64;               // wave row base (2 M-waves)
  const int wn   = (w & 3) * 128;               // wave col base (4 N-waves)
  const int ln   = lane & 15;
  const int kq   = lane >> 4;

  const int e = eidx[b];
  const float* xb = x + (size_t)b * NL * NK;
  const unsigned short* wtb = Wt + (size_t)e * ND * NKP;

  // staging decomposition
  const int arow  = t >> 3;     // A rows 0..63 (p=1 adds 64); 8 f32x4 chunks/row
  const int acol  = t & 7;      // float4 index within the 32-wide k tile
  const int brow  = t >> 2;     // B rows 0..127 (p adds 128); 4 16B slots/row
  const int bslot = t & 3;

  f32x4 acc[4][8];
  const f32x4 zero = {0.f, 0.f, 0.f, 0.f};
#pragma unroll
  for (int mi = 0; mi < 4; ++mi)
#pragma unroll
    for (int ni = 0; ni < 8; ++ni) acc[mi][ni] = zero;

  f32x4 aIn[2];   // A prefetch: 2 x float4 (f32 global)
  uint4 bIn[4];   // B prefetch: 4 x 16B (bf16 global)

// ---- issue global loads for K-tile at K0 into registers (no LDS touch) ----
#define ISSUE_LOADS(K0)                                                       \
  {                                                                           \
    const int kg_ = (K0) + acol * 4;                                          \
    if (kg_ < NK) {                                                           \
      aIn[0] = *(const f32x4*)(xb + (size_t)arow * NK + kg_);                 \
      aIn[1] = *(const f32x4*)(xb + (size_t)(arow + 64) * NK + kg_);          \
    } else {                                                                  \
      aIn[0] = zero; aIn[1] = zero;                                           \
    }                                                                         \
    const unsigned short* bsrc_ = wtb + (K0) + bslot * 8;                     \
    _Pragma("unroll")                                                         \
    for (int p = 0; p < 4; ++p)                                               \
      bIn[p] = *(const uint4*)(bsrc_ + (size_t)(brow + p * 128) * NKP);       \
  }

// ---- convert + write staged registers into LDS buffer BUF ----
#define WRITE_STAGE(BUF)                                                      \
  {                                                                           \
    _Pragma("unroll")                                                         \
    for (int p = 0; p < 2; ++p) {                                             \
      ushort4 h_;                                                             \
      h_.x = f2bf(aIn[p][0]); h_.y = f2bf(aIn[p][1]);                         \
      h_.z = f2bf(aIn[p][2]); h_.w = f2bf(aIn[p][3]);                         \
      *(ushort4*)&As[BUF][(arow + p * 64) * ASTR + acol * 4] = h_;            \
    }                                                                         \
    _Pragma("unroll")                                                         \
    for (int p = 0; p < 4; ++p)                                               \
      *(uint4*)&Bs[BUF][(brow + p * 128) * ASTR + bslot * 8] = bIn[p];        \
  }

// ---- 12 ds_read_b128 + 32 MFMA per wave from buffer BUF ----
#define COMPUTE(BUF)                                                          \
  {                                                                           \
    bf16x8 af_[4];                                                            \
    _Pragma("unroll")                                                         \
    for (int mi = 0; mi < 4; ++mi)                                            \
      af_[mi] = *(bf16x8*)&As[BUF][(wm + mi * 16 + ln) * ASTR + kq * 8];      \
    _Pragma("unroll")                                                         \
    for (int ni = 0; ni < 8; ++ni) {                                          \
      bf16x8 bv_ = *(bf16x8*)&Bs[BUF][(wn + ni * 16 + ln) * ASTR + kq * 8];   \
      _Pragma("unroll")                                                       \
      for (int mi = 0; mi < 4; ++mi)                                          \
        acc[mi][ni] = __builtin_amdgcn_mfma_f32_16x16x32_bf16(                \
            af_[mi], bv_, acc[mi][ni], 0, 0, 0);                              \
    }                                                                         \
  }

  // prologue: stage tile 0
  ISSUE_LOADS(0);
  WRITE_STAGE(0);
  __syncthreads();

  int cur = 0;
  for (int kt = 0; kt < NKT - 1; ++kt) {
    ISSUE_LOADS((kt + 1) * 32);   // prefetch next tile into regs (in flight
    COMPUTE(cur);                 //   across the whole compute phase)
    __syncthreads();              // all waves done reading buf[cur^1]
    WRITE_STAGE(cur ^ 1);         // vmcnt waits land here, after compute
    __syncthreads();              // staged tile visible
    cur ^= 1;
  }
  COMPUTE(cur);                   // last tile, no prefetch

  // ---- epilogue: C/D layout col=lane&15, row=(lane>>4)*4+reg ----
  const float* bt = btot + (size_t)e * ND;
#pragma unroll
  for (int ni = 0; ni < 8; ++ni) {
    const int ncol = wn + ni * 16 + ln;
    const float bias = bt[ncol];
#pragma unroll
    for (int mi = 0; mi < 4; ++mi) {
      const int l0 = wm + mi * 16 + kq * 4;
      float* op = out + ((size_t)b * NL + l0) * ND + ncol;
#pragma unroll
      for (int r = 0; r < 4; ++r)
        __builtin_nontemporal_store(acc[mi][ni][r] + bias, op + (size_t)r * ND);
    }
  }

#undef ISSUE_LOADS
#undef WRITE_STAGE
#undef COMPUTE
}

// ---------------------------------------------------------------------------
// Workspace layout: [0,2048) eidx int[512] | [2048,18432) btot f32[8*512]
//                   [18432, +7602176) Wt bf16[8*512*928]   (~7.27 MiB total)
// ---------------------------------------------------------------------------
extern "C" void kernel_launch(void* const* d_in, const int* in_sizes, int n_in,
                              void* d_out, int out_size, void* d_ws, size_t ws_size,
                              hipStream_t stream) {
  const float* x     = (const float*)d_in[0];  // [512,128,3,300]
  const float* dkp   = (const float*)d_in[1];  // [512,4096]
  const float* Wexp  = (const float*)d_in[2];  // [8,900,512]
  const float* bexp  = (const float*)d_in[3];  // [8,512]
  const float* Wgen  = (const float*)d_in[4];  // [2,900,512]
  const float* bgen  = (const float*)d_in[5];  // [2,512]
  const float* Wgate = (const float*)d_in[6];  // [4096,8]
  const float* bgate = (const float*)d_in[7];  // [8]
  float* out = (float*)d_out;                  // [512,128,512] f32

  int*   eidx = (int*)d_ws;
  float* btot = (float*)((char*)d_ws + 2048);
  unsigned short* Wt = (unsigned short*)((char*)d_ws + 18432);

  gate_kernel<<<NB, 256, 0, stream>>>(dkp, Wgate, bgate, eidx);
  pack_kernel<<<dim3(8, NKT, NE), 256, 0, stream>>>(Wexp, Wgen, Wt);
  bias_kernel<<<16, 256, 0, stream>>>(bexp, bgen, btot);
  gemm_kernel<<<dim3(NB), 512, 0, stream>>>(x, Wt, btot, eidx, out);
}

// Round 2
// 482.721 us; speedup vs baseline: 1.2267x; 1.0418x over previous
//
#include <hip/hip_runtime.h>
#include <stdint.h>

// Problem constants
#define NB   512      // batch
#define NL   128      // cycles per sample (GEMM M)
#define NK   900      // 3*F (GEMM K)
#define NKP  928      // K padded to 29*32
#define NKT  29       // K tiles of 32
#define ND   512      // D_MODEL (GEMM N)
#define BN   256      // per-block N tile (ND split in halves)
#define NDLLM 4096
#define NE   8
#define ASTR 40       // LDS row stride in ushorts (80 B)

typedef __bf16 bf16x8 __attribute__((ext_vector_type(8)));
typedef float  f32x4  __attribute__((ext_vector_type(4)));

// f32 -> bf16 bits, round-to-nearest-even (inputs are finite)
__device__ __forceinline__ unsigned short f2bf(float f) {
  union { float f; uint32_t u; } v; v.f = f;
  uint32_t u = v.u;
  return (unsigned short)((u + 0x7fffu + ((u >> 16) & 1u)) >> 16);
}

// ---------------------------------------------------------------------------
// Kernel 1: gate logits + argmax.  logits[b,e] = DKP[b,:] @ W_gate[:,e] + b_gate[e]
// Top-p with P=0.25,E=8 provably selects exactly argmax with weight exactly 1.0.
// ---------------------------------------------------------------------------
__global__ __launch_bounds__(256) void gate_kernel(
    const float* __restrict__ dkp,    // [NB, 4096]
    const float* __restrict__ Wg,     // [4096, 8]
    const float* __restrict__ bg,     // [8]
    int* __restrict__ eidx)           // [NB]
{
  const int b = blockIdx.x;
  const int t = threadIdx.x;
  float acc[8];
#pragma unroll
  for (int e = 0; e < 8; ++e) acc[e] = 0.f;
  const float* drow = dkp + (size_t)b * NDLLM;
  for (int k = t; k < NDLLM; k += 256) {
    float d = drow[k];
    const float4* w4 = (const float4*)(Wg + (size_t)k * 8);
    float4 w0 = w4[0], w1 = w4[1];
    acc[0] += d * w0.x; acc[1] += d * w0.y; acc[2] += d * w0.z; acc[3] += d * w0.w;
    acc[4] += d * w1.x; acc[5] += d * w1.y; acc[6] += d * w1.z; acc[7] += d * w1.w;
  }
#pragma unroll
  for (int e = 0; e < 8; ++e)
    for (int off = 32; off >= 1; off >>= 1)
      acc[e] += __shfl_down(acc[e], off, 64);

  __shared__ float red[4][8];
  const int wave = t >> 6, lane = t & 63;
  if (lane == 0) {
#pragma unroll
    for (int e = 0; e < 8; ++e) red[wave][e] = acc[e];
  }
  __syncthreads();
  if (t == 0) {
    float best = -1e30f; int bi = 0;
#pragma unroll
    for (int e = 0; e < 8; ++e) {
      float v = red[0][e] + red[1][e] + red[2][e] + red[3][e] + bg[e];
      if (v > best) { best = v; bi = e; }  // strict > matches stable argsort tie-break
    }
    eidx[b] = bi;
  }
}

// ---------------------------------------------------------------------------
// Kernel 2: pack W_tot[e] = W_exp[e] + W_gen[0] + W_gen[1], transposed to
// B^T layout [e][n(512)][k(928)] as bf16 bits, K zero-padded 900->928.
// ---------------------------------------------------------------------------
__global__ __launch_bounds__(256) void pack_kernel(
    const float* __restrict__ Wexp,   // [8, 900, 512]
    const float* __restrict__ Wgen,   // [2, 900, 512]
    unsigned short* __restrict__ Wt)  // [8, 512, 928] bf16 bits
{
  const int nt = blockIdx.x;          // 8 tiles of 64 n
  const int kt = blockIdx.y;          // 29 tiles of 32 k
  const int e  = blockIdx.z;
  const int k0 = kt * 32, n0 = nt * 64;
  __shared__ float tile[32][65];
  const int t = threadIdx.x;
#pragma unroll
  for (int i = 0; i < 8; ++i) {
    int idx = t + i * 256;
    int k = idx >> 6, n = idx & 63;
    int kg = k0 + k;
    float v = 0.f;
    if (kg < NK) {
      size_t off = (size_t)kg * ND + n0 + n;
      v = Wexp[(size_t)e * NK * ND + off] + Wgen[off] + Wgen[(size_t)NK * ND + off];
    }
    tile[k][n] = v;
  }
  __syncthreads();
#pragma unroll
  for (int i = 0; i < 8; ++i) {
    int idx = t + i * 256;
    int n = idx >> 5, k = idx & 31;
    Wt[((size_t)e * ND + n0 + n) * NKP + k0 + k] = f2bf(tile[k][n]);
  }
}

// ---------------------------------------------------------------------------
// Kernel 3: btot[e][d] = b_exp[e][d] + b_gen[0][d] + b_gen[1][d]
// ---------------------------------------------------------------------------
__global__ __launch_bounds__(256) void bias_kernel(
    const float* __restrict__ bexp, const float* __restrict__ bgen,
    float* __restrict__ btot)
{
  int i = blockIdx.x * 256 + threadIdx.x;   // 8*512 = 4096
  int d = i & (ND - 1);
  btot[i] = bexp[i] + bgen[d] + bgen[ND + d];
}

// ---------------------------------------------------------------------------
// Kernel 4: per-batch expert GEMM, N split in halves for 2 blocks/CU.
// Block (b,h): C[b][:, h*256 : h*256+256] = X[b](128x900) @ Wt[e][h-half].
// 512 threads = 8 waves (2M x 4N), per-wave tile 64x64, K-step 32.
// LDS 60 KB (A 2x10, B 2x20, ASTR pad) -> 2 blocks/CU; launch_bounds(512,4)
// caps VGPR at 128 so 16 waves/CU actually schedule. Two co-resident blocks
// fill each other's vmcnt stalls (the occupancy overlap this round targets).
// XCD-pairing swizzle: HW maps raw bid -> XCD (bid%8); decode (b,h) so both
// halves of b land on the same XCD back-to-back => second X[b] read hits L2
// (per-XCD X working set = 8 b * 450 KB = 3.6 MB < 4 MB L2).
// ---------------------------------------------------------------------------
__global__ __launch_bounds__(512, 4) void gemm_kernel(
    const float* __restrict__ x,              // [NB, NL, NK]
    const unsigned short* __restrict__ Wt,    // [8, 512, 928] bf16 bits
    const float* __restrict__ btot,           // [8, 512]
    const int* __restrict__ eidx,             // [NB]
    float* __restrict__ out)                  // [NB, NL, ND] f32
{
  __shared__ unsigned short As[2][NL * ASTR];   // 2 x 10 KB
  __shared__ unsigned short Bs[2][BN * ASTR];   // 2 x 20 KB   (total 60 KB)

  // XCD-pairing decode: raw bid r -> XCD r%8 (HW round-robin model).
  const int r   = blockIdx.x;
  const int s   = r >> 3;
  const int b   = (r & 7) + 8 * (s >> 1);
  const int h   = s & 1;

  const int t    = threadIdx.x;
  const int lane = t & 63;
  const int w    = t >> 6;
  const int wm   = (w >> 2) * 64;               // wave row base (2 M-waves)
  const int wn   = (w & 3) * 64;                // wave col base (4 N-waves)
  const int ln   = lane & 15;
  const int kq   = lane >> 4;

  const int e = eidx[b];
  const float* xb = x + (size_t)b * NL * NK;
  const unsigned short* wtb = Wt + ((size_t)e * ND + (size_t)h * BN) * NKP;

  // staging decomposition (1024 16B-chunks each for A-dst/B; this thread
  // handles chunks t and t+512)
  const int ar0 = t >> 3, ac0 = t & 7;          // A: row, float4-col
  const int br0 = t >> 2, bs0 = t & 3;          // B: row, 16B-slot

  f32x4 acc[4][4];
  const f32x4 zero = {0.f, 0.f, 0.f, 0.f};
#pragma unroll
  for (int mi = 0; mi < 4; ++mi)
#pragma unroll
    for (int ni = 0; ni < 4; ++ni) acc[mi][ni] = zero;

  f32x4 aIn[2];   // A prefetch: 2 x float4 (f32 global, HBM)
  uint4 bIn[2];   // B prefetch: 2 x 16B (bf16 global, mostly L2)

// ---- issue global loads for K-tile at K0 into registers (no LDS touch) ----
#define ISSUE_LOADS(K0)                                                       \
  {                                                                           \
    const int kg_ = (K0) + ac0 * 4;                                           \
    if (kg_ < NK) {                                                           \
      aIn[0] = *(const f32x4*)(xb + (size_t)ar0 * NK + kg_);                  \
      aIn[1] = *(const f32x4*)(xb + (size_t)(ar0 + 64) * NK + kg_);           \
    } else {                                                                  \
      aIn[0] = zero; aIn[1] = zero;                                           \
    }                                                                         \
    const unsigned short* bsrc_ = wtb + (K0) + bs0 * 8;                       \
    bIn[0] = *(const uint4*)(bsrc_ + (size_t)br0 * NKP);                      \
    bIn[1] = *(const uint4*)(bsrc_ + (size_t)(br0 + 128) * NKP);              \
  }

// ---- convert + write staged registers into LDS buffer BUF ----
#define WRITE_STAGE(BUF)                                                      \
  {                                                                           \
    _Pragma("unroll")                                                         \
    for (int p = 0; p < 2; ++p) {                                             \
      ushort4 h_;                                                             \
      h_.x = f2bf(aIn[p][0]); h_.y = f2bf(aIn[p][1]);                         \
      h_.z = f2bf(aIn[p][2]); h_.w = f2bf(aIn[p][3]);                         \
      *(ushort4*)&As[BUF][(ar0 + p * 64) * ASTR + ac0 * 4] = h_;              \
    }                                                                         \
    *(uint4*)&Bs[BUF][(size_t)br0 * ASTR + bs0 * 8] = bIn[0];                 \
    *(uint4*)&Bs[BUF][(size_t)(br0 + 128) * ASTR + bs0 * 8] = bIn[1];         \
  }

// ---- 8 ds_read_b128 + 16 MFMA per wave from buffer BUF ----
// bv persists (4x4 VGPR), af transient: keeps VGPR under the 128 cap.
#define COMPUTE(BUF)                                                          \
  {                                                                           \
    bf16x8 bv_[4];                                                            \
    _Pragma("unroll")                                                         \
    for (int ni = 0; ni < 4; ++ni)                                            \
      bv_[ni] = *(bf16x8*)&Bs[BUF][(wn + ni * 16 + ln) * ASTR + kq * 8];      \
    _Pragma("unroll")                                                         \
    for (int mi = 0; mi < 4; ++mi) {                                          \
      bf16x8 af_ = *(bf16x8*)&As[BUF][(wm + mi * 16 + ln) * ASTR + kq * 8];   \
      _Pragma("unroll")                                                       \
      for (int ni = 0; ni < 4; ++ni)                                          \
        acc[mi][ni] = __builtin_amdgcn_mfma_f32_16x16x32_bf16(                \
            af_, bv_[ni], acc[mi][ni], 0, 0, 0);                              \
    }                                                                         \
  }

  // prologue: stage tile 0
  ISSUE_LOADS(0);
  WRITE_STAGE(0);
  __syncthreads();

  int cur = 0;
  for (int kt = 0; kt < NKT - 1; ++kt) {
    ISSUE_LOADS((kt + 1) * 32);   // prefetch next tile into regs (in flight
    COMPUTE(cur);                 //   across the whole compute phase)
    __syncthreads();              // all waves done reading buf[cur^1]
    WRITE_STAGE(cur ^ 1);         // counted vmcnt waits land here
    __syncthreads();              // staged tile visible
    cur ^= 1;
  }
  COMPUTE(cur);                   // last tile, no prefetch

  // ---- epilogue: C/D layout col=lane&15, row=(lane>>4)*4+reg ----
  // plain stores (r1's nontemporal stores inflated WRITE_SIZE 132->171 MB:
  // unmerged 64B half-lines; write-allocate merges them)
  const float* bt = btot + (size_t)e * ND;
#pragma unroll
  for (int ni = 0; ni < 4; ++ni) {
    const int ncol = h * BN + wn + ni * 16 + ln;
    const float bias = bt[ncol];
#pragma unroll
    for (int mi = 0; mi < 4; ++mi) {
      const int l0 = wm + mi * 16 + kq * 4;
      float* op = out + ((size_t)b * NL + l0) * ND + ncol;
#pragma unroll
      for (int rr = 0; rr < 4; ++rr)
        op[(size_t)rr * ND] = acc[mi][ni][rr] + bias;
    }
  }

#undef ISSUE_LOADS
#undef WRITE_STAGE
#undef COMPUTE
}

// ---------------------------------------------------------------------------
// Workspace layout: [0,2048) eidx int[512] | [2048,18432) btot f32[8*512]
//                   [18432, +7602176) Wt bf16[8*512*928]   (~7.27 MiB total)
// ---------------------------------------------------------------------------
extern "C" void kernel_launch(void* const* d_in, const int* in_sizes, int n_in,
                              void* d_out, int out_size, void* d_ws, size_t ws_size,
                              hipStream_t stream) {
  const float* x     = (const float*)d_in[0];  // [512,128,3,300]
  const float* dkp   = (const float*)d_in[1];  // [512,4096]
  const float* Wexp  = (const float*)d_in[2];  // [8,900,512]
  const float* bexp  = (const float*)d_in[3];  // [8,512]
  const float* Wgen  = (const float*)d_in[4];  // [2,900,512]
  const float* bgen  = (const float*)d_in[5];  // [2,512]
  const float* Wgate = (const float*)d_in[6];  // [4096,8]
  const float* bgate = (const float*)d_in[7];  // [8]
  float* out = (float*)d_out;                  // [512,128,512] f32

  int*   eidx = (int*)d_ws;
  float* btot = (float*)((char*)d_ws + 2048);
  unsigned short* Wt = (unsigned short*)((char*)d_ws + 18432);

  gate_kernel<<<NB, 256, 0, stream>>>(dkp, Wgate, bgate, eidx);
  pack_kernel<<<dim3(8, NKT, NE), 256, 0, stream>>>(Wexp, Wgen, Wt);
  bias_kernel<<<16, 256, 0, stream>>>(bexp, bgen, btot);
  gemm_kernel<<<dim3(NB * 2), 512, 0, stream>>>(x, Wt, btot, eidx, out);
}